// Round 1
// baseline (318.294 us; speedup 1.0000x reference)
//
#include <hip/hip_runtime.h>

// ResNetBlock_MoE: B=64,C=64,H=W=56,E=8,TOPK=2. f32 in / f32 out.
// out = sum_k w_k*relu(bn2(conv2(relu(bn1(conv1(x,e)))))+x), plus dense_w.
//
// R12: conv kernels rebuilt around mfma_f32_32x32x16_bf16.
//  - expert-split waves: wave = (es=w&1, pg=w>>1), 1 expert, 64 out-ch
//    (2 M-tiles of 32), N=32 positions. acc = 2 x f32x16 = 32 VGPR.
//  - A LDS traffic halved (576 reads/block vs 1152) and stored as
//    [k-half][m][8] per K16-slice -> read phases hit 8 distinct bank groups
//    (old layout measured exactly 4 conflict-cycles per ds_read_b128).
//  - A staging double-buffered: 4 chunks x 36KB in 2 bufs (72KB LDS, same
//    2 blocks/CU); chunk c+1 global loads issue BEFORE compute of chunk c,
//    ds_writes after (T14 issue-early/write-late) -> no dead staging drain.
//  - B fragments: one clamp per tap, 16B per lane, N=32 per instr (half the
//    loadB instrs/position of the 16x16 version).
//  - conv2 expert combine via 32KB f32 LDS pass after K-loop (AL is free);
//    conv1 waves write their own expert's h stream directly.

#define BATCH 64
#define CH    64
#define HW_   3136            // 56*56
#define IMG_  (CH*HW_)        // 200704
#define NE    8
#define JOBS  128
#define PWSZ  36864           // per-expert packed weights: 36 slices * 64m * 16k (u16)

typedef unsigned short u16;
typedef __attribute__((ext_vector_type(8))) short short8_t;   // 8 bf16 = 4 VGPR
typedef __attribute__((ext_vector_type(16))) float floatx16;  // 32x32 MFMA acc

__device__ u16   g_xb[(size_t)BATCH * IMG_];  // x bf16 NHWC [b][pos][ch]
__device__ u16   g_h[(size_t)JOBS * IMG_];    // conv1 out bf16 NHWC [job][pos][ch]
__device__ u16   g_pw1[NE * PWSZ];            // packed conv1 w (bn1_s folded)
__device__ u16   g_pw2[NE * PWSZ];            // packed conv2 w (bn2_s folded)
__device__ int   g_eid[JOBS];
__device__ float g_wgt[JOBS];
__device__ float g_pool[BATCH * CH];          // GAP sums (atomic), zeroed by pack

__device__ __forceinline__ u16 f2b(float f) {
    unsigned v; __builtin_memcpy(&v, &f, 4);
    return (u16)((v + 0x7FFFu + ((v >> 16) & 1u)) >> 16);   // RNE
}

// ---------------- weight pre-pack + g_pool zero -----------------------------
// packed[e][s36][h][m][j] = w[e][m][ci][tap]*bn_s[e][m]
//   s36 = tap*4 + kq, ci = kq*16 + h*8 + j   (k-half-major within a slice so
//   the 32x32 A-frag read walks 8 distinct bank groups per phase)
__global__ __launch_bounds__(256) void pack_kernel(
    const float* __restrict__ w1, const float* __restrict__ s1,
    const float* __restrict__ w2, const float* __restrict__ s2)
{
    int idx = blockIdx.x * 256 + threadIdx.x;        // < 589824
    if (idx < BATCH*CH) g_pool[idx] = 0.f;
    int conv = idx / 294912;
    int i2 = idx - conv * 294912;
    int e = i2 / PWSZ;   int r = i2 - e * PWSZ;
    int s36 = r >> 10;   int rem = r & 1023;
    int h = rem >> 9;    int rem2 = rem & 511;
    int m = rem2 >> 3;   int j = rem2 & 7;
    int tap = s36 >> 2;
    int ci = ((s36 & 3) << 4) | (h << 3) | j;
    const float* w  = conv ? w2 : w1;
    const float* sc = conv ? s2 : s1;
    float v = w[((e*64 + m)*64 + ci)*9 + tap] * sc[e*64 + m];
    (conv ? g_pw2 : g_pw1)[i2] = f2b(v);
}

// ---------------- x NCHW f32 -> g_xb NHWC bf16 + GAP partials ---------------
__global__ __launch_bounds__(256) void xconv_kernel(const float* __restrict__ x)
{
    __shared__ u16 T[64*66];          // stride 66 u16 -> conflict-free cols
    int b = blockIdx.y;
    int pos0 = blockIdx.x * 64;
    int tid = threadIdx.x;
    int pin = tid & 63;
    int c0 = tid >> 6;                // 0..3
    const float* xb = x + (size_t)b*IMG_ + pos0 + pin;
    #pragma unroll
    for (int i = 0; i < 16; i++) {
        int ch = c0*16 + i;
        T[pin*66 + ch] = f2b(xb[ch*HW_]);   // coalesced 256B f32 read per instr
    }
    __syncthreads();
    u16* ob = g_xb + (size_t)b*IMG_ + (size_t)pos0*64;
    #pragma unroll
    for (int i = 0; i < 16; i++) {
        int j = tid + i*256;          // 0..4095
        int ch = j & 63, pos = j >> 6;
        ob[pos*64 + ch] = T[pos*66 + ch];   // coalesced 512B write per instr
    }
    // GAP partial: threads 0..63 sum their channel over the 64 positions.
    if (tid < 64) {
        float s = 0.f;
        const float* xc = x + (size_t)b*IMG_ + tid*HW_ + pos0;
        #pragma unroll 4
        for (int p = 0; p < 64; p++) s += xc[p];
        atomicAdd(&g_pool[b*64 + tid], s);
    }
}

// ---------------- gate finalize: pool -> logits -> top2 softmax -------------
__global__ __launch_bounds__(64) void gate_fin_kernel(
    const float* __restrict__ gw, const float* __restrict__ gb,
    float* __restrict__ dw_out)
{
    __shared__ float pooled[CH];
    __shared__ float logits[NE];
    int b = blockIdx.x, t = threadIdx.x;
    pooled[t] = g_pool[b*64 + t] * (1.f/3136.f);
    __syncthreads();
    if (t < NE) {
        float l = gb[t];
        for (int c = 0; c < CH; c++) l += pooled[c] * gw[t*CH + c];
        logits[t] = l;
    }
    __syncthreads();
    if (t == 0) {
        int i1 = 0; float v1 = logits[0];
        for (int e = 1; e < NE; e++) if (logits[e] > v1) { v1 = logits[e]; i1 = e; }
        int i2 = -1; float v2 = -3.4e38f;
        for (int e = 0; e < NE; e++) if (e != i1 && logits[e] > v2) { v2 = logits[e]; i2 = e; }
        float eb = __expf(v2 - v1);
        float wa = 1.f / (1.f + eb), wb = eb / (1.f + eb);
        for (int e = 0; e < NE; e++) dw_out[b*NE + e] = 0.f;
        dw_out[b*NE + i1] = wa;
        dw_out[b*NE + i2] = wb;
        g_eid[2*b] = i1; g_eid[2*b+1] = i2;
        g_wgt[2*b] = wa; g_wgt[2*b+1] = wb;
    }
}

// B-fragment loader for 32x32x16: lane holds pos=l31, k = h*8+j within the
// 16-ch quad kq of tap.  `in` is pre-offset by h*8.  One clamp per tap (CSEd
// across the 4 kq since the K-loop is fully unrolled).
__device__ __forceinline__ short8_t loadB32(
    const u16* __restrict__ in, int gn, int y, int xc, int tap, int kq)
{
    int dy = tap/3 - 1, dxk = tap - (tap/3)*3 - 1;
    int p = gn + dy*56 + dxk;
    bool vld = ((unsigned)(y + dy) < 56u) && ((unsigned)(xc + dxk) < 56u);
    int pc = p < 0 ? 0 : (p > 3135 ? 3135 : p);
    short8_t t = *(const short8_t*)(in + pc*64 + kq*16);
    const short8_t zero = {};
    return vld ? t : zero;
}

// A chunk staging: chunk c = 9 K16-slices x 2 experts = 36KB (2304 16B units).
// Issue loads early (before the chunk's compute), write late (after) -> T14.
__device__ __forceinline__ void stageA_load(
    short8_t* st, const u16* __restrict__ pw0, const u16* __restrict__ pw1,
    int c, int tid)
{
    #pragma unroll
    for (int i = 0; i < 5; i++) {
        int u = i*512 + tid;
        if (u < 2304) {                       // i=4 only for tid<256 (wave-uniform)
            int eslot = u >= 1152;
            int r = u - (eslot ? 1152 : 0);
            st[i] = *(const short8_t*)((eslot ? pw1 : pw0) + c*9216 + r*8);
        }
    }
}
__device__ __forceinline__ void stageA_write(u16* buf, const short8_t* st, int tid)
{
    #pragma unroll
    for (int i = 0; i < 5; i++) {
        int u = i*512 + tid;
        if (u < 2304) {
            int eslot = u >= 1152;
            int r = u - (eslot ? 1152 : 0);
            *(short8_t*)(buf + eslot*9216 + r*8) = st[i];
        }
    }
}

// ---------------- conv1 (expert-split waves) + bn1 + relu -> g_h ------------
__global__ __launch_bounds__(512, 4) void conv1_kernel(const float* __restrict__ b1)
{
    __shared__ u16 AL[2][18432];        // 2 x 36KB double-buffered A chunks
    int tile = blockIdx.x;              // 0..24
    int b    = blockIdx.y;
    int e0 = g_eid[2*b], e1 = g_eid[2*b+1];
    int tid = threadIdx.x;
    int lane = tid & 63, w = tid >> 6;  // 8 waves
    int es = w & 1, pg = w >> 1;        // expert slot, position group
    int l31 = lane & 31, h = lane >> 5;
    int gn = tile*128 + pg*32 + l31;    // may be >= 3136 (tail tile)
    int y = gn/56, xc = gn - y*56;
    int e = es ? e1 : e0;
    const u16* in  = g_xb + (size_t)b*IMG_ + h*8;
    const u16* pw0 = g_pw1 + e0*PWSZ;
    const u16* pw1 = g_pw1 + e1*PWSZ;
    int aOff = es*9216 + h*512 + l31*8; // [es][slice][h][m][j], +mt*256, +j*1024

    floatx16 acc0 = {}, acc1 = {};      // M-tiles 0,1 (out-ch 0..31 / 32..63)
    short8_t B[2];
    B[0] = loadB32(in, gn, y, xc, 0, 0);
    B[1] = loadB32(in, gn, y, xc, 0, 1);

    short8_t st[5];
    stageA_load(st, pw0, pw1, 0, tid);
    stageA_write(&AL[0][0], st, tid);
    __syncthreads();

    #pragma unroll
    for (int c = 0; c < 4; c++) {
        if (c < 3) stageA_load(st, pw0, pw1, c+1, tid);   // issue early
        const u16* ab = &AL[c & 1][0] + aOff;
        #pragma unroll
        for (int j = 0; j < 9; j++) {
            int s = c*9 + j;
            short8_t Bn = {};
            if (s + 2 < 36) Bn = loadB32(in, gn, y, xc, (s+2) >> 2, (s+2) & 3);
            short8_t bb = B[s & 1];
            short8_t a0 = *(const short8_t*)(ab + j*1024);
            short8_t a1 = *(const short8_t*)(ab + j*1024 + 256);
            acc0 = __builtin_amdgcn_mfma_f32_32x32x16_bf16(a0, bb, acc0, 0, 0, 0);
            acc1 = __builtin_amdgcn_mfma_f32_32x32x16_bf16(a1, bb, acc1, 0, 0, 0);
            B[s & 1] = Bn;
        }
        if (c < 3) stageA_write(&AL[(c+1) & 1][0], st, tid);  // write late
        __syncthreads();
    }

    if (gn < HW_) {
        u16* hb = g_h + (size_t)(2*b + es)*IMG_ + (size_t)gn*64;
        #pragma unroll
        for (int mt = 0; mt < 2; mt++) {
            #pragma unroll
            for (int rg = 0; rg < 4; rg++) {
                union { u16 u[4]; uint2 v; } t;
                #pragma unroll
                for (int rr = 0; rr < 4; rr++) {
                    int m = mt*32 + rg*8 + h*4 + rr;   // D row = (reg&3)+8*(reg>>2)+4*h
                    float v = (mt ? acc1 : acc0)[rg*4 + rr] + b1[e*64 + m];
                    t.u[rr] = f2b(fmaxf(v, 0.f));
                }
                *(uint2*)(hb + mt*32 + rg*8 + h*4) = t.v;
            }
        }
    }
}

// ---------------- conv2 + bn2 + residual + cross-wave combine ---------------
__global__ __launch_bounds__(512, 4) void conv2_kernel(
    const float* __restrict__ x, const float* __restrict__ b2,
    float* __restrict__ out)
{
    __shared__ u16 AL[2][18432];
    int tile = 24 - blockIdx.x;         // REVERSED: read newest h first (L2 LIFO)
    int b    = 63 - blockIdx.y;
    int e0 = g_eid[2*b], e1 = g_eid[2*b+1];
    int tid = threadIdx.x;
    int lane = tid & 63, w = tid >> 6;
    int es = w & 1, pg = w >> 1;
    int l31 = lane & 31, h = lane >> 5;
    int gn = tile*128 + pg*32 + l31;
    int y = gn/56, xc = gn - y*56;
    int e = es ? e1 : e0;
    float wgt = g_wgt[2*b + es];
    const u16* in  = g_h + (size_t)(2*b + es)*IMG_ + h*8;  // own expert stream
    const u16* pw0 = g_pw2 + e0*PWSZ;
    const u16* pw1 = g_pw2 + e1*PWSZ;
    int aOff = es*9216 + h*512 + l31*8;

    floatx16 acc0 = {}, acc1 = {};
    short8_t B[2];
    B[0] = loadB32(in, gn, y, xc, 0, 0);
    B[1] = loadB32(in, gn, y, xc, 0, 1);

    short8_t st[5];
    stageA_load(st, pw0, pw1, 0, tid);
    stageA_write(&AL[0][0], st, tid);
    __syncthreads();

    #pragma unroll
    for (int c = 0; c < 4; c++) {
        if (c < 3) stageA_load(st, pw0, pw1, c+1, tid);
        const u16* ab = &AL[c & 1][0] + aOff;
        #pragma unroll
        for (int j = 0; j < 9; j++) {
            int s = c*9 + j;
            short8_t Bn = {};
            if (s + 2 < 36) Bn = loadB32(in, gn, y, xc, (s+2) >> 2, (s+2) & 3);
            short8_t bb = B[s & 1];
            short8_t a0 = *(const short8_t*)(ab + j*1024);
            short8_t a1 = *(const short8_t*)(ab + j*1024 + 256);
            acc0 = __builtin_amdgcn_mfma_f32_32x32x16_bf16(a0, bb, acc0, 0, 0, 0);
            acc1 = __builtin_amdgcn_mfma_f32_32x32x16_bf16(a1, bb, acc1, 0, 0, 0);
            B[s & 1] = Bn;
        }
        if (c < 3) stageA_write(&AL[(c+1) & 1][0], st, tid);
        __syncthreads();                 // final barrier also frees AL for combine
    }

    // combine: e0 waves drop w0*relu(y0+x) into LDS (32KB), e1 waves add+store.
    float* P = (float*)&AL[0][0];        // [pg][m][l31] f32, 2-way-free banks
    const float* xb = x + (size_t)b*IMG_ + gn;
    if (es == 0 && gn < HW_) {
        #pragma unroll
        for (int mt = 0; mt < 2; mt++)
            #pragma unroll
            for (int rg = 0; rg < 4; rg++)
                #pragma unroll
                for (int rr = 0; rr < 4; rr++) {
                    int m = mt*32 + rg*8 + h*4 + rr;
                    float v = (mt ? acc1 : acc0)[rg*4 + rr] + b2[e*64 + m]
                              + xb[(size_t)m*HW_];
                    P[(pg*64 + m)*32 + l31] = wgt * fmaxf(v, 0.f);
                }
    }
    __syncthreads();
    if (es == 1 && gn < HW_) {
        float* ob = out + (size_t)b*IMG_ + gn;
        #pragma unroll
        for (int mt = 0; mt < 2; mt++)
            #pragma unroll
            for (int rg = 0; rg < 4; rg++)
                #pragma unroll
                for (int rr = 0; rr < 4; rr++) {
                    int m = mt*32 + rg*8 + h*4 + rr;
                    float v = (mt ? acc1 : acc0)[rg*4 + rr] + b2[e*64 + m]
                              + xb[(size_t)m*HW_];
                    ob[(size_t)m*HW_] = wgt * fmaxf(v, 0.f)
                                        + P[(pg*64 + m)*32 + l31];
                }
    }
}

extern "C" void kernel_launch(void* const* d_in, const int* in_sizes, int n_in,
                              void* d_out, int out_size, void* d_ws, size_t ws_size,
                              hipStream_t stream) {
    const float* x   = (const float*)d_in[0];
    const float* gw  = (const float*)d_in[1];
    const float* gb  = (const float*)d_in[2];
    const float* w1  = (const float*)d_in[3];
    const float* s1  = (const float*)d_in[4];
    const float* b1  = (const float*)d_in[5];
    const float* w2  = (const float*)d_in[6];
    const float* s2  = (const float*)d_in[7];
    const float* b2  = (const float*)d_in[8];
    float* out = (float*)d_out;
    float* dw  = out + (size_t)BATCH * IMG_;   // dense_w region of d_out (f32)

    (void)d_ws; (void)ws_size;                 // zero d_ws usage (R1/R2 aborts)

    hipLaunchKernelGGL(pack_kernel, dim3(2304), dim3(256), 0, stream, w1, s1, w2, s2);
    hipLaunchKernelGGL(xconv_kernel, dim3(49, BATCH), dim3(256), 0, stream, x);
    hipLaunchKernelGGL(gate_fin_kernel, dim3(BATCH), dim3(64), 0, stream, gw, gb, dw);
    hipLaunchKernelGGL(conv1_kernel, dim3(25, BATCH), dim3(512), 0, stream, b1);
    hipLaunchKernelGGL(conv2_kernel, dim3(25, BATCH), dim3(512), 0, stream, x, b2, out);
}

// Round 2
// 303.739 us; speedup vs baseline: 1.0479x; 1.0479x over previous
//
#include <hip/hip_runtime.h>

// ResNetBlock_MoE: B=64,C=64,H=W=56,E=8,TOPK=2. f32 in / f32 out.
// out = sum_k w_k*relu(bn2(conv2(relu(bn1(conv1(x,e)))))+x), plus dense_w.
//
// R13: R12 post-mortem — conflict-free A layout worked (SQ_LDS_BANK_CONFLICT
// 7.37M -> 0) but dur regressed 87->111us: per-step MFMA work halved (2x8cy
// vs 8x5cy) while B prefetch stayed depth-2, so B-load latency (g_h/g_xb are
// L3/HBM resident, ~600-900cy) went uncovered (~280cy). Fix: rolling B
// prefetch depth 8 (+24 VGPR, stays <=128 so 4 waves/SIMD holds). B loads
// are register-dest so they remain in flight across chunk barriers.

#define BATCH 64
#define CH    64
#define HW_   3136            // 56*56
#define IMG_  (CH*HW_)        // 200704
#define NE    8
#define JOBS  128
#define PWSZ  36864           // per-expert packed weights: 36 slices * 64m * 16k (u16)
#define BDEPTH 8              // rolling B-prefetch depth (steps)

typedef unsigned short u16;
typedef __attribute__((ext_vector_type(8))) short short8_t;   // 8 bf16 = 4 VGPR
typedef __attribute__((ext_vector_type(16))) float floatx16;  // 32x32 MFMA acc

__device__ u16   g_xb[(size_t)BATCH * IMG_];  // x bf16 NHWC [b][pos][ch]
__device__ u16   g_h[(size_t)JOBS * IMG_];    // conv1 out bf16 NHWC [job][pos][ch]
__device__ u16   g_pw1[NE * PWSZ];            // packed conv1 w (bn1_s folded)
__device__ u16   g_pw2[NE * PWSZ];            // packed conv2 w (bn2_s folded)
__device__ int   g_eid[JOBS];
__device__ float g_wgt[JOBS];
__device__ float g_pool[BATCH * CH];          // GAP sums (atomic), zeroed by pack

__device__ __forceinline__ u16 f2b(float f) {
    unsigned v; __builtin_memcpy(&v, &f, 4);
    return (u16)((v + 0x7FFFu + ((v >> 16) & 1u)) >> 16);   // RNE
}

// ---------------- weight pre-pack + g_pool zero -----------------------------
// packed[e][s36][h][m][j] = w[e][m][ci][tap]*bn_s[e][m]
//   s36 = tap*4 + kq, ci = kq*16 + h*8 + j   (k-half-major within a slice so
//   the 32x32 A-frag read walks 8 distinct bank groups per phase)
__global__ __launch_bounds__(256) void pack_kernel(
    const float* __restrict__ w1, const float* __restrict__ s1,
    const float* __restrict__ w2, const float* __restrict__ s2)
{
    int idx = blockIdx.x * 256 + threadIdx.x;        // < 589824
    if (idx < BATCH*CH) g_pool[idx] = 0.f;
    int conv = idx / 294912;
    int i2 = idx - conv * 294912;
    int e = i2 / PWSZ;   int r = i2 - e * PWSZ;
    int s36 = r >> 10;   int rem = r & 1023;
    int h = rem >> 9;    int rem2 = rem & 511;
    int m = rem2 >> 3;   int j = rem2 & 7;
    int tap = s36 >> 2;
    int ci = ((s36 & 3) << 4) | (h << 3) | j;
    const float* w  = conv ? w2 : w1;
    const float* sc = conv ? s2 : s1;
    float v = w[((e*64 + m)*64 + ci)*9 + tap] * sc[e*64 + m];
    (conv ? g_pw2 : g_pw1)[i2] = f2b(v);
}

// ---------------- x NCHW f32 -> g_xb NHWC bf16 + GAP partials ---------------
__global__ __launch_bounds__(256) void xconv_kernel(const float* __restrict__ x)
{
    __shared__ u16 T[64*66];          // stride 66 u16 -> conflict-free cols
    int b = blockIdx.y;
    int pos0 = blockIdx.x * 64;
    int tid = threadIdx.x;
    int pin = tid & 63;
    int c0 = tid >> 6;                // 0..3
    const float* xb = x + (size_t)b*IMG_ + pos0 + pin;
    #pragma unroll
    for (int i = 0; i < 16; i++) {
        int ch = c0*16 + i;
        T[pin*66 + ch] = f2b(xb[ch*HW_]);   // coalesced 256B f32 read per instr
    }
    __syncthreads();
    u16* ob = g_xb + (size_t)b*IMG_ + (size_t)pos0*64;
    #pragma unroll
    for (int i = 0; i < 16; i++) {
        int j = tid + i*256;          // 0..4095
        int ch = j & 63, pos = j >> 6;
        ob[pos*64 + ch] = T[pos*66 + ch];   // coalesced 512B write per instr
    }
    // GAP partial: threads 0..63 sum their channel over the 64 positions.
    if (tid < 64) {
        float s = 0.f;
        const float* xc = x + (size_t)b*IMG_ + tid*HW_ + pos0;
        #pragma unroll 4
        for (int p = 0; p < 64; p++) s += xc[p];
        atomicAdd(&g_pool[b*64 + tid], s);
    }
}

// ---------------- gate finalize: pool -> logits -> top2 softmax -------------
__global__ __launch_bounds__(64) void gate_fin_kernel(
    const float* __restrict__ gw, const float* __restrict__ gb,
    float* __restrict__ dw_out)
{
    __shared__ float pooled[CH];
    __shared__ float logits[NE];
    int b = blockIdx.x, t = threadIdx.x;
    pooled[t] = g_pool[b*64 + t] * (1.f/3136.f);
    __syncthreads();
    if (t < NE) {
        float l = gb[t];
        for (int c = 0; c < CH; c++) l += pooled[c] * gw[t*CH + c];
        logits[t] = l;
    }
    __syncthreads();
    if (t == 0) {
        int i1 = 0; float v1 = logits[0];
        for (int e = 1; e < NE; e++) if (logits[e] > v1) { v1 = logits[e]; i1 = e; }
        int i2 = -1; float v2 = -3.4e38f;
        for (int e = 0; e < NE; e++) if (e != i1 && logits[e] > v2) { v2 = logits[e]; i2 = e; }
        float eb = __expf(v2 - v1);
        float wa = 1.f / (1.f + eb), wb = eb / (1.f + eb);
        for (int e = 0; e < NE; e++) dw_out[b*NE + e] = 0.f;
        dw_out[b*NE + i1] = wa;
        dw_out[b*NE + i2] = wb;
        g_eid[2*b] = i1; g_eid[2*b+1] = i2;
        g_wgt[2*b] = wa; g_wgt[2*b+1] = wb;
    }
}

// B-fragment loader for 32x32x16: lane holds pos=l31, k = h*8+j within the
// 16-ch quad kq of tap.  `in` is pre-offset by h*8.  One clamp per tap (CSEd
// across the 4 kq since the K-loop is fully unrolled).
__device__ __forceinline__ short8_t loadB32(
    const u16* __restrict__ in, int gn, int y, int xc, int tap, int kq)
{
    int dy = tap/3 - 1, dxk = tap - (tap/3)*3 - 1;
    int p = gn + dy*56 + dxk;
    bool vld = ((unsigned)(y + dy) < 56u) && ((unsigned)(xc + dxk) < 56u);
    int pc = p < 0 ? 0 : (p > 3135 ? 3135 : p);
    short8_t t = *(const short8_t*)(in + pc*64 + kq*16);
    const short8_t zero = {};
    return vld ? t : zero;
}

// A chunk staging: chunk c = 9 K16-slices x 2 experts = 36KB (2304 16B units).
// Issue loads early (before the chunk's compute), write late (after) -> T14.
__device__ __forceinline__ void stageA_load(
    short8_t* st, const u16* __restrict__ pw0, const u16* __restrict__ pw1,
    int c, int tid)
{
    #pragma unroll
    for (int i = 0; i < 5; i++) {
        int u = i*512 + tid;
        if (u < 2304) {                       // i=4 only for tid<256 (wave-uniform)
            int eslot = u >= 1152;
            int r = u - (eslot ? 1152 : 0);
            st[i] = *(const short8_t*)((eslot ? pw1 : pw0) + c*9216 + r*8);
        }
    }
}
__device__ __forceinline__ void stageA_write(u16* buf, const short8_t* st, int tid)
{
    #pragma unroll
    for (int i = 0; i < 5; i++) {
        int u = i*512 + tid;
        if (u < 2304) {
            int eslot = u >= 1152;
            int r = u - (eslot ? 1152 : 0);
            *(short8_t*)(buf + eslot*9216 + r*8) = st[i];
        }
    }
}

// ---------------- conv1 (expert-split waves) + bn1 + relu -> g_h ------------
__global__ __launch_bounds__(512, 4) void conv1_kernel(const float* __restrict__ b1)
{
    __shared__ u16 AL[2][18432];        // 2 x 36KB double-buffered A chunks
    int tile = blockIdx.x;              // 0..24
    int b    = blockIdx.y;
    int e0 = g_eid[2*b], e1 = g_eid[2*b+1];
    int tid = threadIdx.x;
    int lane = tid & 63, w = tid >> 6;  // 8 waves
    int es = w & 1, pg = w >> 1;        // expert slot, position group
    int l31 = lane & 31, h = lane >> 5;
    int gn = tile*128 + pg*32 + l31;    // may be >= 3136 (tail tile)
    int y = gn/56, xc = gn - y*56;
    int e = es ? e1 : e0;
    const u16* in  = g_xb + (size_t)b*IMG_ + h*8;
    const u16* pw0 = g_pw1 + e0*PWSZ;
    const u16* pw1 = g_pw1 + e1*PWSZ;
    int aOff = es*9216 + h*512 + l31*8; // [es][slice][h][m][j], +mt*256, +j*1024

    floatx16 acc0 = {}, acc1 = {};      // M-tiles 0,1 (out-ch 0..31 / 32..63)
    short8_t B[BDEPTH];
    #pragma unroll
    for (int s = 0; s < BDEPTH; s++)
        B[s] = loadB32(in, gn, y, xc, s >> 2, s & 3);

    short8_t st[5];
    stageA_load(st, pw0, pw1, 0, tid);
    stageA_write(&AL[0][0], st, tid);
    __syncthreads();

    #pragma unroll
    for (int c = 0; c < 4; c++) {
        if (c < 3) stageA_load(st, pw0, pw1, c+1, tid);   // issue early
        const u16* ab = &AL[c & 1][0] + aOff;
        #pragma unroll
        for (int j = 0; j < 9; j++) {
            int s = c*9 + j;
            short8_t bb = B[s % BDEPTH];
            short8_t a0 = *(const short8_t*)(ab + j*1024);
            short8_t a1 = *(const short8_t*)(ab + j*1024 + 256);
            acc0 = __builtin_amdgcn_mfma_f32_32x32x16_bf16(a0, bb, acc0, 0, 0, 0);
            acc1 = __builtin_amdgcn_mfma_f32_32x32x16_bf16(a1, bb, acc1, 0, 0, 0);
            int sp = s + BDEPTH;                          // rolling refill
            short8_t Bn = {};
            if (sp < 36) Bn = loadB32(in, gn, y, xc, sp >> 2, sp & 3);
            B[s % BDEPTH] = Bn;
        }
        if (c < 3) stageA_write(&AL[(c+1) & 1][0], st, tid);  // write late
        __syncthreads();
    }

    if (gn < HW_) {
        u16* hb = g_h + (size_t)(2*b + es)*IMG_ + (size_t)gn*64;
        #pragma unroll
        for (int mt = 0; mt < 2; mt++) {
            #pragma unroll
            for (int rg = 0; rg < 4; rg++) {
                union { u16 u[4]; uint2 v; } t;
                #pragma unroll
                for (int rr = 0; rr < 4; rr++) {
                    int m = mt*32 + rg*8 + h*4 + rr;   // D row = (reg&3)+8*(reg>>2)+4*h
                    float v = (mt ? acc1 : acc0)[rg*4 + rr] + b1[e*64 + m];
                    t.u[rr] = f2b(fmaxf(v, 0.f));
                }
                *(uint2*)(hb + mt*32 + rg*8 + h*4) = t.v;
            }
        }
    }
}

// ---------------- conv2 + bn2 + residual + cross-wave combine ---------------
__global__ __launch_bounds__(512, 4) void conv2_kernel(
    const float* __restrict__ x, const float* __restrict__ b2,
    float* __restrict__ out)
{
    __shared__ u16 AL[2][18432];
    int tile = 24 - blockIdx.x;         // REVERSED: read newest h first (L2 LIFO)
    int b    = 63 - blockIdx.y;
    int e0 = g_eid[2*b], e1 = g_eid[2*b+1];
    int tid = threadIdx.x;
    int lane = tid & 63, w = tid >> 6;
    int es = w & 1, pg = w >> 1;
    int l31 = lane & 31, h = lane >> 5;
    int gn = tile*128 + pg*32 + l31;
    int y = gn/56, xc = gn - y*56;
    int e = es ? e1 : e0;
    float wgt = g_wgt[2*b + es];
    const u16* in  = g_h + (size_t)(2*b + es)*IMG_ + h*8;  // own expert stream
    const u16* pw0 = g_pw2 + e0*PWSZ;
    const u16* pw1 = g_pw2 + e1*PWSZ;
    int aOff = es*9216 + h*512 + l31*8;

    floatx16 acc0 = {}, acc1 = {};
    short8_t B[BDEPTH];
    #pragma unroll
    for (int s = 0; s < BDEPTH; s++)
        B[s] = loadB32(in, gn, y, xc, s >> 2, s & 3);

    short8_t st[5];
    stageA_load(st, pw0, pw1, 0, tid);
    stageA_write(&AL[0][0], st, tid);
    __syncthreads();

    #pragma unroll
    for (int c = 0; c < 4; c++) {
        if (c < 3) stageA_load(st, pw0, pw1, c+1, tid);
        const u16* ab = &AL[c & 1][0] + aOff;
        #pragma unroll
        for (int j = 0; j < 9; j++) {
            int s = c*9 + j;
            short8_t bb = B[s % BDEPTH];
            short8_t a0 = *(const short8_t*)(ab + j*1024);
            short8_t a1 = *(const short8_t*)(ab + j*1024 + 256);
            acc0 = __builtin_amdgcn_mfma_f32_32x32x16_bf16(a0, bb, acc0, 0, 0, 0);
            acc1 = __builtin_amdgcn_mfma_f32_32x32x16_bf16(a1, bb, acc1, 0, 0, 0);
            int sp = s + BDEPTH;
            short8_t Bn = {};
            if (sp < 36) Bn = loadB32(in, gn, y, xc, sp >> 2, sp & 3);
            B[s % BDEPTH] = Bn;
        }
        if (c < 3) stageA_write(&AL[(c+1) & 1][0], st, tid);
        __syncthreads();                 // final barrier also frees AL for combine
    }

    // combine: e0 waves drop w0*relu(y0+x) into LDS (32KB), e1 waves add+store.
    float* P = (float*)&AL[0][0];        // [pg][m][l31] f32, 2-way-free banks
    const float* xb = x + (size_t)b*IMG_ + gn;
    if (es == 0 && gn < HW_) {
        #pragma unroll
        for (int mt = 0; mt < 2; mt++)
            #pragma unroll
            for (int rg = 0; rg < 4; rg++)
                #pragma unroll
                for (int rr = 0; rr < 4; rr++) {
                    int m = mt*32 + rg*8 + h*4 + rr;
                    float v = (mt ? acc1 : acc0)[rg*4 + rr] + b2[e*64 + m]
                              + xb[(size_t)m*HW_];
                    P[(pg*64 + m)*32 + l31] = wgt * fmaxf(v, 0.f);
                }
    }
    __syncthreads();
    if (es == 1 && gn < HW_) {
        float* ob = out + (size_t)b*IMG_ + gn;
        #pragma unroll
        for (int mt = 0; mt < 2; mt++)
            #pragma unroll
            for (int rg = 0; rg < 4; rg++)
                #pragma unroll
                for (int rr = 0; rr < 4; rr++) {
                    int m = mt*32 + rg*8 + h*4 + rr;
                    float v = (mt ? acc1 : acc0)[rg*4 + rr] + b2[e*64 + m]
                              + xb[(size_t)m*HW_];
                    ob[(size_t)m*HW_] = wgt * fmaxf(v, 0.f)
                                        + P[(pg*64 + m)*32 + l31];
                }
    }
}

extern "C" void kernel_launch(void* const* d_in, const int* in_sizes, int n_in,
                              void* d_out, int out_size, void* d_ws, size_t ws_size,
                              hipStream_t stream) {
    const float* x   = (const float*)d_in[0];
    const float* gw  = (const float*)d_in[1];
    const float* gb  = (const float*)d_in[2];
    const float* w1  = (const float*)d_in[3];
    const float* s1  = (const float*)d_in[4];
    const float* b1  = (const float*)d_in[5];
    const float* w2  = (const float*)d_in[6];
    const float* s2  = (const float*)d_in[7];
    const float* b2  = (const float*)d_in[8];
    float* out = (float*)d_out;
    float* dw  = out + (size_t)BATCH * IMG_;   // dense_w region of d_out (f32)

    (void)d_ws; (void)ws_size;                 // zero d_ws usage (R1/R2 aborts)

    hipLaunchKernelGGL(pack_kernel, dim3(2304), dim3(256), 0, stream, w1, s1, w2, s2);
    hipLaunchKernelGGL(xconv_kernel, dim3(49, BATCH), dim3(256), 0, stream, x);
    hipLaunchKernelGGL(gate_fin_kernel, dim3(BATCH), dim3(64), 0, stream, gw, gb, dw);
    hipLaunchKernelGGL(conv1_kernel, dim3(25, BATCH), dim3(512), 0, stream, b1);
    hipLaunchKernelGGL(conv2_kernel, dim3(25, BATCH), dim3(512), 0, stream, x, b2, out);
}